// Round 12
// baseline (286.620 us; speedup 1.0000x reference)
//
#include <hip/hip_runtime.h>

typedef unsigned int u32;
typedef unsigned long long u64;

#define NPT   8192      // points per batch
#define NBAT  2
#define NCH   64        // C == D
#define NKNN  16
#define QPW   2         // queries per wave-pair in knn

static constexpr size_t MB = 1024 * 1024;
static constexpr size_t KB = 1024;
static constexpr size_t OFF_KNN   = 0;                       // [B][N][16] int  = 1 MB
static constexpr size_t OFF_XYZW  = 1 * MB;                  // [B][N] float4   = 256 KB
static constexpr size_t OFF_BN1P  = OFF_XYZW + 512 * KB;     // [512][16] dbl   = 64 KB
static constexpr size_t OFF_BN1S  = OFF_BN1P + 64 * KB;      // [16] f
static constexpr size_t OFF_BN2P  = OFF_BN1S + 64 * KB;      // [64][128] dbl   = 64 KB
static constexpr size_t OFF_BN2S  = OFF_BN2P + 64 * KB;      // [128] f
static constexpr size_t OFF_LWT   = OFF_BN2S + 64 * KB;      // linwT [512][64] = 128 KB
static constexpr size_t OFF_DIFFT = 2 * MB;                  // [B*N][64] f = 4 MB
static constexpr size_t OFF_PCT   = 6 * MB;                  // [B*N][64] f
static constexpr size_t OFF_QT    = 14 * MB;
static constexpr size_t OFF_KT    = 18 * MB;
static constexpr size_t OFF_VT    = 22 * MB;                 // end 26 MB

// ---------------------------------------------------------------- prep: xyzw pack + diffT + linwT
__global__ __launch_bounds__(256) void prep(const float* __restrict__ xyz,
                                            const float* __restrict__ cost,
                                            const float* __restrict__ points,
                                            const float* __restrict__ lin_w,
                                            float4* __restrict__ xyzw,
                                            float* __restrict__ diffT,
                                            float* __restrict__ linwT) {
  __shared__ float t[64][65];
  int blk = blockIdx.x;
  int lx = threadIdx.x & 63, ly = threadIdx.x >> 6;
  if (blk < 256) {                      // diffT transpose tiles
    int b = blk >> 7, n0 = (blk & 127) * 64;
    size_t bo = (size_t)b * NCH * NPT;
    #pragma unroll
    for (int i = 0; i < 16; i++) {
      int c = ly + i * 4;
      size_t idx = bo + (size_t)c * NPT + n0 + lx;
      t[c][lx] = cost[idx] - points[idx];
    }
    __syncthreads();
    #pragma unroll
    for (int i = 0; i < 16; i++) {
      int n = ly + i * 4;
      diffT[(((size_t)b << 13) + n0 + n) * 64 + lx] = t[lx][n];
    }
  } else if (blk < 264) {               // linwT transpose tiles
    int f0 = (blk - 256) * 64;
    #pragma unroll
    for (int i = 0; i < 16; i++) {
      int c = ly + i * 4;
      t[c][lx] = lin_w[(size_t)c * 512 + f0 + lx];
    }
    __syncthreads();
    #pragma unroll
    for (int i = 0; i < 16; i++) {
      int fy = ly + i * 4;
      linwT[(size_t)(f0 + fy) * 64 + lx] = t[lx][fy];
    }
  } else {                              // pack xyz
    int g = (blk - 264) * 256 + threadIdx.x;   // 0..B*N-1
    int b = g >> 13, n = g & (NPT - 1);
    const float* xb = xyz + (size_t)b * 3 * NPT;
    float x = xb[n], y = xb[NPT + n], z = xb[2 * NPT + n];
    float sq = __fadd_rn(__fadd_rn(__fmul_rn(x, x), __fmul_rn(y, y)), __fmul_rn(z, z));
    xyzw[g] = make_float4(x, y, z, sq);
  }
}

// ---------------------------------------------------------------- knn (exhaustive, split-halves + merge)
__device__ __forceinline__ u64 sort64(u64 key, int lane) {
  #pragma unroll
  for (int k = 2; k <= 64; k <<= 1) {
    #pragma unroll
    for (int j = k >> 1; j > 0; j >>= 1) {
      u64 o = __shfl_xor(key, j);
      bool up = ((lane & k) == 0);
      bool lower = ((lane & j) == 0);
      bool keepmin = (lower == up);
      u64 mn = (o < key) ? o : key;
      u64 mx = (o < key) ? key : o;
      key = keepmin ? mn : mx;
    }
  }
  return key;
}

__device__ __forceinline__ u32 knn_dist(float qx, float qy, float qz, float qs,
                                        float4 cp) {
  float dot = __fadd_rn(__fadd_rn(__fmul_rn(qx, cp.x), __fmul_rn(qy, cp.y)),
                        __fmul_rn(qz, cp.z));
  float d = __fsub_rn(__fadd_rn(qs, cp.w), __fmul_rn(2.0f, dot));
  u32 db = __float_as_uint(d);
  db ^= ((u32)((int)db >> 31) | 0x80000000u);   // sortable-uint transform
  return db;
}

// Each PAIR of waves handles QPW=2 queries: wave half=0 scans candidate rows
// 0..63, half=1 scans rows 64..127; local top-16s merged exactly via sort64.
// Global top-16 element has local rank<=16 in its half (subset property);
// halves disjoint -> no duplicate keys; (dist,idx) key = numpy tie-break.
__global__ __launch_bounds__(256) void knn_kernel(const float4* __restrict__ xyzw,
                                                  int* __restrict__ knn) {
  __shared__ u64 buf[4][QPW][64];      // 4 KB
  const int tid = threadIdx.x;
  const int w = tid >> 6, lane = tid & 63;
  const int pair = blockIdx.x * 2 + (w >> 1);  // 4096 blocks -> 8192 pairs
  const int half = w & 1;
  const int b = pair >> 12;
  const int q0 = (pair & 4095) * 2;
  const float4* xb = xyzw + ((size_t)b << 13);
  const u64 ltm = (1ull << lane) - 1ull;
  const int cbase = half << 12;        // this wave's candidate base (0 or 4096)

  float qx[QPW], qy[QPW], qz[QPW], qs[QPW];
  u32 tau[QPW];
  int cnt[QPW];
  float4 nxt = xb[cbase + lane];       // first row of this half (also warm-start)
  #pragma unroll
  for (int i = 0; i < QPW; i++) {
    float4 p = xb[q0 + i];
    qx[i] = p.x; qy[i] = p.y; qz[i] = p.z; qs[i] = p.w;
    cnt[i] = 0;
    // warm-start: tau = 16th smallest distance among this half's first row
    u32 db = knn_dist(qx[i], qy[i], qz[i], qs[i], nxt);
    u64 ks = sort64((((u64)db) << 13) | (u32)(cbase + lane), lane);
    u64 k15 = __shfl(ks, 15);
    tau[i] = (u32)(k15 >> 13);
  }
  for (int r = 0; r < 64; ++r) {
    float4 cp = nxt;
    int rn = (r < 63) ? (r + 1) : 63;
    nxt = xb[cbase + rn * 64 + lane];  // register prefetch of next row
    u32 ci = (u32)(cbase + r * 64 + lane);
    #pragma unroll
    for (int i = 0; i < QPW; i++) {
      u32 db = knn_dist(qx[i], qy[i], qz[i], qs[i], cp);
      bool pass = db <= tau[i];
      u64 m = __ballot(pass);
      if (!m) continue;                // common late-scan case: skip key build
      u64 key = (((u64)db) << 13) | ci;
      while (m) {                      // wave-uniform loop, no drops possible
        int pr = (int)__popcll(m & ltm);   // my rank among passers
        int pc = (int)__popcll(m);
        int room = 64 - cnt[i];
        if (pass && pr < room) buf[w][i][cnt[i] + pr] = key;
        if (pc <= room) { cnt[i] += pc; break; }
        // buffer now full (cnt..63 written by the pr<room lanes)
        cnt[i] = 64;
        __builtin_amdgcn_wave_barrier();
        u64 ck = buf[w][i][lane];          // compact: sort 64, keep 16
        ck = sort64(ck, lane);
        __builtin_amdgcn_wave_barrier();
        if (lane < 16) buf[w][i][lane] = ck;
        cnt[i] = 16;
        u64 k15 = __shfl(ck, 15);
        tau[i] = (u32)(k15 >> 13);
        __builtin_amdgcn_wave_barrier();
        // drop written lanes; re-filter survivors against the new tau
        pass = pass && (pr >= room) && (db <= tau[i]);
        m = __ballot(pass);
      }
    }
  }
  // local top-16 per half -> LDS
  #pragma unroll
  for (int i = 0; i < QPW; i++) {
    __builtin_amdgcn_wave_barrier();
    u64 key = (lane < cnt[i]) ? buf[w][i][lane] : ~0ull;
    key = sort64(key, lane);
    __builtin_amdgcn_wave_barrier();
    if (lane < 16) buf[w][i][lane] = key;
  }
  __syncthreads();
  // merge the two halves (waves 0&1 -> pair A, waves 2&3 -> pair B)
  if (half == 0) {
    #pragma unroll
    for (int i = 0; i < QPW; i++) {
      u64 key = (lane < 16) ? buf[w][i][lane]
              : (lane < 32) ? buf[w + 1][i][lane - 16] : ~0ull;
      key = sort64(key, lane);
      if (lane < NKNN)
        knn[(((size_t)b << 13) + q0 + i) * NKNN + lane] = (int)(key & 8191u);
    }
  }
}

// ---------------------------------------------------------------- bn1 stats (weightnet out)
__global__ __launch_bounds__(256) void bn1_partial(const float4* __restrict__ xyzw,
                                                   const int* __restrict__ knn,
                                                   const float* __restrict__ wn_w,
                                                   const float* __restrict__ wn_b,
                                                   double* __restrict__ bn1p) {
  float wm[24], wb8[8];
  #pragma unroll
  for (int i = 0; i < 24; i++) wm[i] = wn_w[i];
  #pragma unroll
  for (int o = 0; o < 8; o++) wb8[o] = wn_b[o];
  double s[8] = {0,0,0,0,0,0,0,0}, ss[8] = {0,0,0,0,0,0,0,0};
  int base = blockIdx.x * 512 + threadIdx.x * 2;
  for (int it = 0; it < 2; ++it) {
    int g = base + it;
    int nb = knn[g];
    int b = g >> 17;
    int n = (g >> 4) & (NPT - 1);
    float4 pq = xyzw[(b << 13) + n];
    float4 pc = xyzw[(b << 13) + nb];
    float ox = pc.x - pq.x, oy = pc.y - pq.y, oz = pc.z - pq.z;
    #pragma unroll
    for (int o = 0; o < 8; o++) {
      float u = fmaf(wm[3*o], ox, fmaf(wm[3*o+1], oy, wm[3*o+2] * oz)) + wb8[o];
      s[o] += u; ss[o] += (double)u * (double)u;
    }
  }
  int lane = threadIdx.x & 63, w = threadIdx.x >> 6;
  __shared__ double red[4][16];
  #pragma unroll
  for (int o = 0; o < 8; o++) {
    double v = s[o], v2 = ss[o];
    #pragma unroll
    for (int off = 32; off; off >>= 1) { v += __shfl_down(v, off); v2 += __shfl_down(v2, off); }
    if (lane == 0) { red[w][o] = v; red[w][8 + o] = v2; }
  }
  __syncthreads();
  if (threadIdx.x < 16) {
    double v = red[0][threadIdx.x] + red[1][threadIdx.x] + red[2][threadIdx.x] + red[3][threadIdx.x];
    bn1p[blockIdx.x * 16 + threadIdx.x] = v;
  }
}

__global__ __launch_bounds__(256) void bn1_final(const double* __restrict__ bn1p,
                                                 const float* __restrict__ wn_g,
                                                 const float* __restrict__ wn_be,
                                                 float* __restrict__ bn1s) {
  __shared__ double red[16][16];
  int e = threadIdx.x & 15, grp = threadIdx.x >> 4;
  double v = 0;
  for (int j = grp; j < 512; j += 16) v += bn1p[j * 16 + e];
  red[grp][e] = v;
  __syncthreads();
  if (threadIdx.x < 8) {
    int o = threadIdx.x;
    double S = 0, SS = 0;
    #pragma unroll
    for (int g2 = 0; g2 < 16; g2++) { S += red[g2][o]; SS += red[g2][8 + o]; }
    const double CNT = 262144.0;
    double m = S / CNT;
    double var = SS / CNT - m * m;
    double rs = 1.0 / sqrt(var + 1e-5);
    double g = (double)wn_g[o];
    bn1s[o] = (float)(g * rs);
    bn1s[8 + o] = (float)((double)wn_be[o] - m * g * rs);
  }
}

// ---------------------------------------------------------------- pointconv fused
__global__ __launch_bounds__(256) void pointconv(const float4* __restrict__ xyzw,
                                                 const int* __restrict__ knn,
                                                 const float* __restrict__ diffT,
                                                 const float* __restrict__ linwT,
                                                 const float* __restrict__ lin_b,
                                                 const float* __restrict__ bn1s,
                                                 const float* __restrict__ wn_w,
                                                 const float* __restrict__ wn_b,
                                                 float* __restrict__ pcT) {
  __shared__ __align__(16) float Al[16][520];   // agg rows, 33.3 KB
  const int tid = threadIdx.x;
  const int w = tid >> 6, lane = tid & 63;
  const size_t p0 = (size_t)blockIdx.x * 16;    // 1024 blocks
  const int b = (int)(p0 >> 13);

  float wm[24], wb8[8], s1[8], sh1[8];
  #pragma unroll
  for (int i = 0; i < 24; i++) wm[i] = wn_w[i];
  #pragma unroll
  for (int o = 0; o < 8; o++) { wb8[o] = wn_b[o]; s1[o] = bn1s[o]; sh1[o] = bn1s[8 + o]; }
  const float4* xb = xyzw + ((size_t)b << 13);

  #pragma unroll
  for (int p = 0; p < 4; p++) {
    int pt = w * 4 + p;
    size_t g = p0 + pt;
    int n = (int)(g & (NPT - 1));
    float4 pq = xb[n];
    const int* kn = knn + g * NKNN;
    int nbs[16];
    #pragma unroll
    for (int k = 0; k < 4; k++) {
      int4 k4 = ((const int4*)kn)[k];
      nbs[4*k] = k4.x; nbs[4*k+1] = k4.y; nbs[4*k+2] = k4.z; nbs[4*k+3] = k4.w;
    }
    float acc[8] = {0,0,0,0,0,0,0,0};
    #pragma unroll
    for (int k = 0; k < NKNN; k++) {
      int nb = nbs[k];
      float4 pcd = xb[nb];
      float ox = pcd.x - pq.x, oy = pcd.y - pq.y, oz = pcd.z - pq.z;
      float gv = diffT[((((size_t)b << 13) + nb) << 6) + lane];
      #pragma unroll
      for (int o = 0; o < 8; o++) {
        float u = fmaf(wm[3*o], ox, fmaf(wm[3*o+1], oy, wm[3*o+2] * oz)) + wb8[o];
        u = fmaf(u, s1[o], sh1[o]);
        u = (u >= 0.f) ? u : 0.1f * u;
        acc[o] = fmaf(gv, u, acc[o]);
      }
    }
    *(float4*)&Al[pt][lane * 8]     = make_float4(acc[0], acc[1], acc[2], acc[3]);
    *(float4*)&Al[pt][lane * 8 + 4] = make_float4(acc[4], acc[5], acc[6], acc[7]);
  }
  __builtin_amdgcn_wave_barrier();   // phase 2 reads only this wave's rows

  const int co4 = (lane & 15) * 4;
  const int fs = (lane >> 4) * 128;
  float acc[4][4];
  #pragma unroll
  for (int i = 0; i < 4; i++)
    #pragma unroll
    for (int j = 0; j < 4; j++) acc[i][j] = 0.f;

  for (int fo = 0; fo < 128; fo += 4) {
    int f = fs + fo;
    float4 af[4];
    #pragma unroll
    for (int i = 0; i < 4; i++) af[i] = *(const float4*)&Al[w * 4 + i][f];
    #pragma unroll
    for (int ff = 0; ff < 4; ff++) {
      float4 wv = *(const float4*)&linwT[(size_t)(f + ff) * 64 + co4];
      #pragma unroll
      for (int i = 0; i < 4; i++) {
        float a = (ff == 0) ? af[i].x : (ff == 1) ? af[i].y : (ff == 2) ? af[i].z : af[i].w;
        acc[i][0] = fmaf(a, wv.x, acc[i][0]);
        acc[i][1] = fmaf(a, wv.y, acc[i][1]);
        acc[i][2] = fmaf(a, wv.z, acc[i][2]);
        acc[i][3] = fmaf(a, wv.w, acc[i][3]);
      }
    }
  }
  #pragma unroll
  for (int i = 0; i < 4; i++)
    #pragma unroll
    for (int j = 0; j < 4; j++) {
      float v = acc[i][j];
      v += __shfl_xor(v, 16);
      v += __shfl_xor(v, 32);
      acc[i][j] = v;
    }
  if (lane < 16) {
    float4 lb = *(const float4*)&lin_b[co4];
    #pragma unroll
    for (int i = 0; i < 4; i++) {
      float4 r = make_float4(acc[i][0] + lb.x, acc[i][1] + lb.y,
                             acc[i][2] + lb.z, acc[i][3] + lb.w);
      *(float4*)&pcT[(p0 + w * 4 + i) * 64 + co4] = r;
    }
  }
}

// ---------------------------------------------------------------- bn2 stats
__global__ __launch_bounds__(256) void bn2_partial(const float* __restrict__ pcT,
                                                   double* __restrict__ bn2p) {
  int c = threadIdx.x & 63, rg = threadIdx.x >> 6;
  double s = 0, ss = 0;
  size_t r0 = (size_t)blockIdx.x * 256;
  for (int r = rg; r < 256; r += 4) {
    float v = pcT[(r0 + r) * 64 + c];
    s += v; ss += (double)v * (double)v;
  }
  __shared__ double red[4][64][2];
  red[rg][c][0] = s; red[rg][c][1] = ss;
  __syncthreads();
  if (rg == 0) {
    double S  = red[0][c][0] + red[1][c][0] + red[2][c][0] + red[3][c][0];
    double SS = red[0][c][1] + red[1][c][1] + red[2][c][1] + red[3][c][1];
    bn2p[blockIdx.x * 128 + c] = S;
    bn2p[blockIdx.x * 128 + 64 + c] = SS;
  }
}

__global__ __launch_bounds__(256) void bn2_final(const double* __restrict__ bn2p,
                                                 const float* __restrict__ bn_g,
                                                 const float* __restrict__ bn_be,
                                                 float* __restrict__ bn2s) {
  __shared__ double red[2][128];
  int e = threadIdx.x & 127, grp = threadIdx.x >> 7;
  double v = 0;
  for (int j = grp; j < 64; j += 2) v += bn2p[j * 128 + e];
  red[grp][e] = v;
  __syncthreads();
  if (threadIdx.x < 64) {
    int c = threadIdx.x;
    double S  = red[0][c] + red[1][c];
    double SS = red[0][64 + c] + red[1][64 + c];
    const double CNT = 16384.0;
    double m = S / CNT, var = SS / CNT - m * m;
    double rs = 1.0 / sqrt(var + 1e-5);
    double g = (double)bn_g[c];
    bn2s[c] = (float)(g * rs);
    bn2s[64 + c] = (float)((double)bn_be[c] - m * g * rs);
  }
}

// ---------------------------------------------------------------- cost_mod + q/k/v projections (fused)
__global__ __launch_bounds__(192) void qkv_cm(const float* __restrict__ cost,
    const float* __restrict__ pcT, const float* __restrict__ bn2s,
    const float* __restrict__ wq, const float* __restrict__ bq,
    const float* __restrict__ wk, const float* __restrict__ bk,
    const float* __restrict__ wv, const float* __restrict__ bv,
    float* __restrict__ qT, float* __restrict__ kT, float* __restrict__ vT) {
  int w = threadIdx.x / 64, lane = threadIdx.x & 63;
  const float* W  = (w == 0) ? wq : (w == 1) ? wk : wv;
  const float* Bb = (w == 0) ? bq : (w == 1) ? bk : bv;
  float* O        = (w == 0) ? qT : (w == 1) ? kT : vT;
  float wr[64];
  #pragma unroll
  for (int j = 0; j < 16; j++) {
    float4 a = *(const float4*)(W + (size_t)lane * 64 + 4 * j);
    wr[4*j] = a.x; wr[4*j+1] = a.y; wr[4*j+2] = a.z; wr[4*j+3] = a.w;
  }
  float bl = Bb[lane];
  __shared__ float cm[4][64];
  if (w == 0) {                        // stage cost_mod rows for 4 points
    float sc = bn2s[lane], sh = bn2s[64 + lane];
    #pragma unroll
    for (int pi = 0; pi < 4; ++pi) {
      size_t g = (size_t)blockIdx.x * 4 + pi;
      int b = (int)(g >> 13), n = (int)(g & (NPT - 1));
      float cv = cost[(size_t)b * NCH * NPT + (size_t)lane * NPT + n];
      float ca = fmaf(pcT[g * 64 + lane], sc, sh);
      ca = (ca >= 0.f) ? ca : 0.1f * ca;
      cm[pi][lane] = cv + ca;
    }
  }
  __syncthreads();
  #pragma unroll
  for (int pi = 0; pi < 4; ++pi) {
    size_t g = (size_t)blockIdx.x * 4 + pi;
    float acc = 0.f;
    #pragma unroll
    for (int j = 0; j < 16; j++) {
      float4 cv = *(const float4*)&cm[pi][4 * j];
      acc = fmaf(wr[4*j], cv.x, fmaf(wr[4*j+1], cv.y, fmaf(wr[4*j+2], cv.z, fmaf(wr[4*j+3], cv.w, acc))));
    }
    O[g * 64 + lane] = acc + bl;
  }
}

// ---------------------------------------------------------------- attention
__global__ __launch_bounds__(256) void attn_k(const float4* __restrict__ xyzw,
    const int* __restrict__ knn, const float* __restrict__ qT,
    const float* __restrict__ kT, const float* __restrict__ vT,
    const float* __restrict__ wpos, const float* __restrict__ bpos,
    float* __restrict__ out) {
  int w = threadIdx.x >> 6, lane = threadIdx.x & 63;
  size_t g = (size_t)blockIdx.x * 4 + w;
  int b = (int)(g >> 13), n = (int)(g & (NPT - 1));
  const float4* xb = xyzw + ((size_t)b << 13);
  float wp0 = wpos[3 * lane], wp1 = wpos[3 * lane + 1], wp2 = wpos[3 * lane + 2];
  float bp = bpos[lane];
  float4 pq = xb[n];
  float qd = qT[g * 64 + lane];
  const int* kn = knn + g * NKNN;
  float sc[16], vp[16];
  #pragma unroll
  for (int k = 0; k < 16; k++) {
    int nb = kn[k];
    float4 pcd = xb[nb];
    float ox = pcd.x - pq.x, oy = pcd.y - pq.y, oz = pcd.z - pq.z;
    float pos = fmaf(wp0, ox, fmaf(wp1, oy, wp2 * oz)) + bp;
    size_t nbi = (((size_t)b << 13) + nb) * 64 + lane;
    float kk = kT[nbi] + pos;
    float vv = vT[nbi] + pos;
    float p = qd * kk;
    #pragma unroll
    for (int off = 32; off; off >>= 1) p += __shfl_xor(p, off);
    sc[k] = p * 0.125f;
    vp[k] = vv;
  }
  float m = sc[0];
  #pragma unroll
  for (int k = 1; k < 16; k++) m = fmaxf(m, sc[k]);
  float sum = 0.f;
  #pragma unroll
  for (int k = 0; k < 16; k++) { sc[k] = __expf(sc[k] - m); sum += sc[k]; }
  float inv = 1.0f / sum;
  float od = 0.f;
  #pragma unroll
  for (int k = 0; k < 16; k++) od = fmaf(sc[k] * inv, vp[k], od);
  out[((size_t)b * 64 + lane) * NPT + n] = od;
}

// ---------------------------------------------------------------- launch
extern "C" void kernel_launch(void* const* d_in, const int* in_sizes, int n_in,
                              void* d_out, int out_size, void* d_ws, size_t ws_size,
                              hipStream_t stream) {
  (void)in_sizes; (void)n_in; (void)out_size; (void)ws_size;
  const float* xyz    = (const float*)d_in[0];
  const float* points = (const float*)d_in[1];
  const float* cost   = (const float*)d_in[2];
  const float* wn_w   = (const float*)d_in[3];
  const float* wn_b   = (const float*)d_in[4];
  const float* wn_g   = (const float*)d_in[5];
  const float* wn_be  = (const float*)d_in[6];
  const float* lin_w  = (const float*)d_in[7];
  const float* lin_b  = (const float*)d_in[8];
  const float* bn_g   = (const float*)d_in[9];
  const float* bn_be  = (const float*)d_in[10];
  const float* wq     = (const float*)d_in[11];
  const float* bq     = (const float*)d_in[12];
  const float* wk     = (const float*)d_in[13];
  const float* bk     = (const float*)d_in[14];
  const float* wv     = (const float*)d_in[15];
  const float* bv     = (const float*)d_in[16];
  const float* wpos   = (const float*)d_in[17];
  const float* bpos   = (const float*)d_in[18];
  float* out = (float*)d_out;
  char* ws = (char*)d_ws;

  int*    knn  = (int*)   (ws + OFF_KNN);
  float4* xyzw = (float4*)(ws + OFF_XYZW);
  double* bn1p = (double*)(ws + OFF_BN1P);
  float*  bn1s = (float*) (ws + OFF_BN1S);
  double* bn2p = (double*)(ws + OFF_BN2P);
  float*  bn2s = (float*) (ws + OFF_BN2S);
  float*  lwT  = (float*) (ws + OFF_LWT);
  float* diffT = (float*) (ws + OFF_DIFFT);
  float* pcT   = (float*) (ws + OFF_PCT);
  float* qT    = (float*) (ws + OFF_QT);
  float* kT    = (float*) (ws + OFF_KT);
  float* vT    = (float*) (ws + OFF_VT);

  prep       <<<dim3(328),     dim3(256),   0, stream>>>(xyz, cost, points, lin_w,
                                                         xyzw, diffT, lwT);
  knn_kernel <<<dim3(4096),    dim3(256),   0, stream>>>(xyzw, knn);
  bn1_partial<<<dim3(512),     dim3(256),   0, stream>>>(xyzw, knn, wn_w, wn_b, bn1p);
  bn1_final  <<<dim3(1),       dim3(256),   0, stream>>>(bn1p, wn_g, wn_be, bn1s);
  pointconv  <<<dim3(1024),    dim3(256),   0, stream>>>(xyzw, knn, diffT, lwT, lin_b,
                                                         bn1s, wn_w, wn_b, pcT);
  bn2_partial<<<dim3(64),      dim3(256),   0, stream>>>(pcT, bn2p);
  bn2_final  <<<dim3(1),       dim3(256),   0, stream>>>(bn2p, bn_g, bn_be, bn2s);
  qkv_cm     <<<dim3(4096),    dim3(192),   0, stream>>>(cost, pcT, bn2s, wq, bq, wk, bk,
                                                         wv, bv, qT, kT, vT);
  attn_k     <<<dim3(4096),    dim3(256),   0, stream>>>(xyzw, knn, qT, kT, vT, wpos, bpos, out);
}

// Round 13
// 257.852 us; speedup vs baseline: 1.1116x; 1.1116x over previous
//
#include <hip/hip_runtime.h>

typedef unsigned int u32;
typedef unsigned long long u64;

#define NPT   8192      // points per batch
#define NBAT  2
#define NCH   64        // C == D
#define NKNN  16
#define QPW   2         // queries per wave in knn

static constexpr size_t MB = 1024 * 1024;
static constexpr size_t KB = 1024;
static constexpr size_t OFF_KNN   = 0;                       // [B][N][16] int  = 1 MB
static constexpr size_t OFF_XYZW  = 1 * MB;                  // [B][N] float4   = 256 KB
static constexpr size_t OFF_BN1P  = OFF_XYZW + 512 * KB;     // [512][16] dbl   = 64 KB
static constexpr size_t OFF_BN1S  = OFF_BN1P + 64 * KB;      // [16] f
static constexpr size_t OFF_BN2P  = OFF_BN1S + 64 * KB;      // [64][128] dbl   = 64 KB
static constexpr size_t OFF_BN2S  = OFF_BN2P + 64 * KB;      // [128] f
static constexpr size_t OFF_LWT   = OFF_BN2S + 64 * KB;      // linwT [512][64] = 128 KB
static constexpr size_t OFF_DIFFT = 2 * MB;                  // [B*N][64] f = 4 MB
static constexpr size_t OFF_PCT   = 6 * MB;                  // [B*N][64] f
static constexpr size_t OFF_QT    = 14 * MB;
static constexpr size_t OFF_KT    = 18 * MB;
static constexpr size_t OFF_VT    = 22 * MB;                 // end 26 MB

// ---------------------------------------------------------------- prep: xyzw pack + diffT + linwT
__global__ __launch_bounds__(256) void prep(const float* __restrict__ xyz,
                                            const float* __restrict__ cost,
                                            const float* __restrict__ points,
                                            const float* __restrict__ lin_w,
                                            float4* __restrict__ xyzw,
                                            float* __restrict__ diffT,
                                            float* __restrict__ linwT) {
  __shared__ float t[64][65];
  int blk = blockIdx.x;
  int lx = threadIdx.x & 63, ly = threadIdx.x >> 6;
  if (blk < 256) {                      // diffT transpose tiles
    int b = blk >> 7, n0 = (blk & 127) * 64;
    size_t bo = (size_t)b * NCH * NPT;
    #pragma unroll
    for (int i = 0; i < 16; i++) {
      int c = ly + i * 4;
      size_t idx = bo + (size_t)c * NPT + n0 + lx;
      t[c][lx] = cost[idx] - points[idx];
    }
    __syncthreads();
    #pragma unroll
    for (int i = 0; i < 16; i++) {
      int n = ly + i * 4;
      diffT[(((size_t)b << 13) + n0 + n) * 64 + lx] = t[lx][n];
    }
  } else if (blk < 264) {               // linwT transpose tiles
    int f0 = (blk - 256) * 64;
    #pragma unroll
    for (int i = 0; i < 16; i++) {
      int c = ly + i * 4;
      t[c][lx] = lin_w[(size_t)c * 512 + f0 + lx];
    }
    __syncthreads();
    #pragma unroll
    for (int i = 0; i < 16; i++) {
      int fy = ly + i * 4;
      linwT[(size_t)(f0 + fy) * 64 + lx] = t[lx][fy];
    }
  } else {                              // pack xyz
    int g = (blk - 264) * 256 + threadIdx.x;   // 0..B*N-1
    int b = g >> 13, n = g & (NPT - 1);
    const float* xb = xyz + (size_t)b * 3 * NPT;
    float x = xb[n], y = xb[NPT + n], z = xb[2 * NPT + n];
    float sq = __fadd_rn(__fadd_rn(__fmul_rn(x, x), __fmul_rn(y, y)), __fmul_rn(z, z));
    xyzw[g] = make_float4(x, y, z, sq);
  }
}

// ---------------------------------------------------------------- knn (R5 shape; float-domain compare)
__device__ __forceinline__ u64 sort64(u64 key, int lane) {
  #pragma unroll
  for (int k = 2; k <= 64; k <<= 1) {
    #pragma unroll
    for (int j = k >> 1; j > 0; j >>= 1) {
      u64 o = __shfl_xor(key, j);
      bool up = ((lane & k) == 0);
      bool lower = ((lane & j) == 0);
      bool keepmin = (lower == up);
      u64 mn = (o < key) ? o : key;
      u64 mx = (o < key) ? key : o;
      key = keepmin ? mn : mx;
    }
  }
  return key;
}

__device__ __forceinline__ float knn_dist_f(float qx, float qy, float qz, float qs,
                                            float4 cp) {
  float dot = __fadd_rn(__fadd_rn(__fmul_rn(qx, cp.x), __fmul_rn(qy, cp.y)),
                        __fmul_rn(qz, cp.z));
  return __fsub_rn(__fadd_rn(qs, cp.w), __fmul_rn(2.0f, dot));
}

__device__ __forceinline__ u32 sortable(float d) {
  u32 db = __float_as_uint(d);
  return db ^ ((u32)((int)db >> 31) | 0x80000000u);
}

__device__ __forceinline__ float inv_sortable(u32 y) {
  u32 x = (y & 0x80000000u) ? (y ^ 0x80000000u) : ~y;
  return __uint_as_float(x);
}

__global__ __launch_bounds__(256) void knn_kernel(const float4* __restrict__ xyzw,
                                                  int* __restrict__ knn) {
  __shared__ u64 buf[4][QPW][64];      // 4 KB
  const int tid = threadIdx.x;
  const int w = tid >> 6, lane = tid & 63;
  const int blk = blockIdx.x;          // 2048 blocks
  const int b = blk >> 10;
  const int q0 = (blk & 1023) * 8 + w * QPW;
  const float4* xb = xyzw + ((size_t)b << 13);
  const u64 ltm = (1ull << lane) - 1ull;

  float qx[QPW], qy[QPW], qz[QPW], qs[QPW];
  u32 tau[QPW];
  float tauf[QPW];                     // exact decoded tau (float domain)
  int cnt[QPW];
  float4 nxt = xb[lane];               // row 0 (also warm-start candidates)
  #pragma unroll
  for (int i = 0; i < QPW; i++) {
    float4 p = xb[q0 + i];
    qx[i] = p.x; qy[i] = p.y; qz[i] = p.z; qs[i] = p.w;
    cnt[i] = 0;
    // warm-start: tau = 16th smallest distance among candidates 0..63
    u32 db = sortable(knn_dist_f(qx[i], qy[i], qz[i], qs[i], nxt));
    u64 ks = sort64((((u64)db) << 13) | (u32)lane, lane);
    u64 k15 = __shfl(ks, 15);
    tau[i] = (u32)(k15 >> 13);
    tauf[i] = inv_sortable(tau[i]);
  }
  for (int r = 0; r < 128; ++r) {
    float4 cp = nxt;
    int rn = (r < 127) ? (r + 1) : 127;
    nxt = xb[rn * 64 + lane];          // register prefetch of next row
    u32 ci = (u32)(r * 64 + lane);
    #pragma unroll
    for (int i = 0; i < QPW; i++) {
      // float-domain compare: sortable transform is strictly monotone, so
      // d <= tauf  <=>  sortable(d) <= tau  -> identical pass set.
      float d = knn_dist_f(qx[i], qy[i], qz[i], qs[i], cp);
      bool pass = d <= tauf[i];
      u64 m = __ballot(pass);
      if (!m) continue;                // common case late in scan
      u32 db = sortable(d);            // key build only when some lane passes
      u64 key = (((u64)db) << 13) | ci;
      while (m) {                      // wave-uniform loop, no drops possible
        int pr = (int)__popcll(m & ltm);   // my rank among passers
        int pc = (int)__popcll(m);
        int room = 64 - cnt[i];
        if (pass && pr < room) buf[w][i][cnt[i] + pr] = key;
        if (pc <= room) { cnt[i] += pc; break; }
        // buffer now full (cnt..63 written by the pr<room lanes)
        cnt[i] = 64;
        __builtin_amdgcn_wave_barrier();
        u64 ck = buf[w][i][lane];          // compact: sort 64, keep 16
        ck = sort64(ck, lane);
        __builtin_amdgcn_wave_barrier();
        if (lane < 16) buf[w][i][lane] = ck;
        cnt[i] = 16;
        u64 k15 = __shfl(ck, 15);
        tau[i] = (u32)(k15 >> 13);
        tauf[i] = inv_sortable(tau[i]);
        __builtin_amdgcn_wave_barrier();
        // drop written lanes; re-filter survivors against the new tau
        pass = pass && (pr >= room) && (db <= tau[i]);
        m = __ballot(pass);
      }
    }
  }
  #pragma unroll
  for (int i = 0; i < QPW; i++) {
    __builtin_amdgcn_wave_barrier();
    u64 key = (lane < cnt[i]) ? buf[w][i][lane] : ~0ull;
    key = sort64(key, lane);
    if (lane < NKNN)
      knn[(((size_t)b << 13) + q0 + i) * NKNN + lane] = (int)(key & 8191u);
  }
}

// ---------------------------------------------------------------- bn1 stats (weightnet out)
__global__ __launch_bounds__(256) void bn1_partial(const float4* __restrict__ xyzw,
                                                   const int* __restrict__ knn,
                                                   const float* __restrict__ wn_w,
                                                   const float* __restrict__ wn_b,
                                                   double* __restrict__ bn1p) {
  float wm[24], wb8[8];
  #pragma unroll
  for (int i = 0; i < 24; i++) wm[i] = wn_w[i];
  #pragma unroll
  for (int o = 0; o < 8; o++) wb8[o] = wn_b[o];
  double s[8] = {0,0,0,0,0,0,0,0}, ss[8] = {0,0,0,0,0,0,0,0};
  int base = blockIdx.x * 512 + threadIdx.x * 2;
  for (int it = 0; it < 2; ++it) {
    int g = base + it;
    int nb = knn[g];
    int b = g >> 17;
    int n = (g >> 4) & (NPT - 1);
    float4 pq = xyzw[(b << 13) + n];
    float4 pc = xyzw[(b << 13) + nb];
    float ox = pc.x - pq.x, oy = pc.y - pq.y, oz = pc.z - pq.z;
    #pragma unroll
    for (int o = 0; o < 8; o++) {
      float u = fmaf(wm[3*o], ox, fmaf(wm[3*o+1], oy, wm[3*o+2] * oz)) + wb8[o];
      s[o] += u; ss[o] += (double)u * (double)u;
    }
  }
  int lane = threadIdx.x & 63, w = threadIdx.x >> 6;
  __shared__ double red[4][16];
  #pragma unroll
  for (int o = 0; o < 8; o++) {
    double v = s[o], v2 = ss[o];
    #pragma unroll
    for (int off = 32; off; off >>= 1) { v += __shfl_down(v, off); v2 += __shfl_down(v2, off); }
    if (lane == 0) { red[w][o] = v; red[w][8 + o] = v2; }
  }
  __syncthreads();
  if (threadIdx.x < 16) {
    double v = red[0][threadIdx.x] + red[1][threadIdx.x] + red[2][threadIdx.x] + red[3][threadIdx.x];
    bn1p[blockIdx.x * 16 + threadIdx.x] = v;
  }
}

__global__ __launch_bounds__(256) void bn1_final(const double* __restrict__ bn1p,
                                                 const float* __restrict__ wn_g,
                                                 const float* __restrict__ wn_be,
                                                 float* __restrict__ bn1s) {
  __shared__ double red[16][16];
  int e = threadIdx.x & 15, grp = threadIdx.x >> 4;
  double v = 0;
  for (int j = grp; j < 512; j += 16) v += bn1p[j * 16 + e];
  red[grp][e] = v;
  __syncthreads();
  if (threadIdx.x < 8) {
    int o = threadIdx.x;
    double S = 0, SS = 0;
    #pragma unroll
    for (int g2 = 0; g2 < 16; g2++) { S += red[g2][o]; SS += red[g2][8 + o]; }
    const double CNT = 262144.0;
    double m = S / CNT;
    double var = SS / CNT - m * m;
    double rs = 1.0 / sqrt(var + 1e-5);
    double g = (double)wn_g[o];
    bn1s[o] = (float)(g * rs);
    bn1s[8 + o] = (float)((double)wn_be[o] - m * g * rs);
  }
}

// ---------------------------------------------------------------- pointconv fused
__global__ __launch_bounds__(256) void pointconv(const float4* __restrict__ xyzw,
                                                 const int* __restrict__ knn,
                                                 const float* __restrict__ diffT,
                                                 const float* __restrict__ linwT,
                                                 const float* __restrict__ lin_b,
                                                 const float* __restrict__ bn1s,
                                                 const float* __restrict__ wn_w,
                                                 const float* __restrict__ wn_b,
                                                 float* __restrict__ pcT) {
  __shared__ __align__(16) float Al[16][520];   // agg rows, 33.3 KB
  const int tid = threadIdx.x;
  const int w = tid >> 6, lane = tid & 63;
  const size_t p0 = (size_t)blockIdx.x * 16;    // 1024 blocks
  const int b = (int)(p0 >> 13);

  float wm[24], wb8[8], s1[8], sh1[8];
  #pragma unroll
  for (int i = 0; i < 24; i++) wm[i] = wn_w[i];
  #pragma unroll
  for (int o = 0; o < 8; o++) { wb8[o] = wn_b[o]; s1[o] = bn1s[o]; sh1[o] = bn1s[8 + o]; }
  const float4* xb = xyzw + ((size_t)b << 13);

  #pragma unroll
  for (int p = 0; p < 4; p++) {
    int pt = w * 4 + p;
    size_t g = p0 + pt;
    int n = (int)(g & (NPT - 1));
    float4 pq = xb[n];
    const int* kn = knn + g * NKNN;
    int nbs[16];
    #pragma unroll
    for (int k = 0; k < 4; k++) {
      int4 k4 = ((const int4*)kn)[k];
      nbs[4*k] = k4.x; nbs[4*k+1] = k4.y; nbs[4*k+2] = k4.z; nbs[4*k+3] = k4.w;
    }
    float acc[8] = {0,0,0,0,0,0,0,0};
    #pragma unroll
    for (int k = 0; k < NKNN; k++) {
      int nb = nbs[k];
      float4 pcd = xb[nb];
      float ox = pcd.x - pq.x, oy = pcd.y - pq.y, oz = pcd.z - pq.z;
      float gv = diffT[((((size_t)b << 13) + nb) << 6) + lane];
      #pragma unroll
      for (int o = 0; o < 8; o++) {
        float u = fmaf(wm[3*o], ox, fmaf(wm[3*o+1], oy, wm[3*o+2] * oz)) + wb8[o];
        u = fmaf(u, s1[o], sh1[o]);
        u = (u >= 0.f) ? u : 0.1f * u;
        acc[o] = fmaf(gv, u, acc[o]);
      }
    }
    *(float4*)&Al[pt][lane * 8]     = make_float4(acc[0], acc[1], acc[2], acc[3]);
    *(float4*)&Al[pt][lane * 8 + 4] = make_float4(acc[4], acc[5], acc[6], acc[7]);
  }
  __builtin_amdgcn_wave_barrier();   // phase 2 reads only this wave's rows

  const int co4 = (lane & 15) * 4;
  const int fs = (lane >> 4) * 128;
  float acc[4][4];
  #pragma unroll
  for (int i = 0; i < 4; i++)
    #pragma unroll
    for (int j = 0; j < 4; j++) acc[i][j] = 0.f;

  for (int fo = 0; fo < 128; fo += 4) {
    int f = fs + fo;
    float4 af[4];
    #pragma unroll
    for (int i = 0; i < 4; i++) af[i] = *(const float4*)&Al[w * 4 + i][f];
    #pragma unroll
    for (int ff = 0; ff < 4; ff++) {
      float4 wv = *(const float4*)&linwT[(size_t)(f + ff) * 64 + co4];
      #pragma unroll
      for (int i = 0; i < 4; i++) {
        float a = (ff == 0) ? af[i].x : (ff == 1) ? af[i].y : (ff == 2) ? af[i].z : af[i].w;
        acc[i][0] = fmaf(a, wv.x, acc[i][0]);
        acc[i][1] = fmaf(a, wv.y, acc[i][1]);
        acc[i][2] = fmaf(a, wv.z, acc[i][2]);
        acc[i][3] = fmaf(a, wv.w, acc[i][3]);
      }
    }
  }
  #pragma unroll
  for (int i = 0; i < 4; i++)
    #pragma unroll
    for (int j = 0; j < 4; j++) {
      float v = acc[i][j];
      v += __shfl_xor(v, 16);
      v += __shfl_xor(v, 32);
      acc[i][j] = v;
    }
  if (lane < 16) {
    float4 lb = *(const float4*)&lin_b[co4];
    #pragma unroll
    for (int i = 0; i < 4; i++) {
      float4 r = make_float4(acc[i][0] + lb.x, acc[i][1] + lb.y,
                             acc[i][2] + lb.z, acc[i][3] + lb.w);
      *(float4*)&pcT[(p0 + w * 4 + i) * 64 + co4] = r;
    }
  }
}

// ---------------------------------------------------------------- bn2 stats
__global__ __launch_bounds__(256) void bn2_partial(const float* __restrict__ pcT,
                                                   double* __restrict__ bn2p) {
  int c = threadIdx.x & 63, rg = threadIdx.x >> 6;
  double s = 0, ss = 0;
  size_t r0 = (size_t)blockIdx.x * 256;
  for (int r = rg; r < 256; r += 4) {
    float v = pcT[(r0 + r) * 64 + c];
    s += v; ss += (double)v * (double)v;
  }
  __shared__ double red[4][64][2];
  red[rg][c][0] = s; red[rg][c][1] = ss;
  __syncthreads();
  if (rg == 0) {
    double S  = red[0][c][0] + red[1][c][0] + red[2][c][0] + red[3][c][0];
    double SS = red[0][c][1] + red[1][c][1] + red[2][c][1] + red[3][c][1];
    bn2p[blockIdx.x * 128 + c] = S;
    bn2p[blockIdx.x * 128 + 64 + c] = SS;
  }
}

__global__ __launch_bounds__(256) void bn2_final(const double* __restrict__ bn2p,
                                                 const float* __restrict__ bn_g,
                                                 const float* __restrict__ bn_be,
                                                 float* __restrict__ bn2s) {
  __shared__ double red[2][128];
  int e = threadIdx.x & 127, grp = threadIdx.x >> 7;
  double v = 0;
  for (int j = grp; j < 64; j += 2) v += bn2p[j * 128 + e];
  red[grp][e] = v;
  __syncthreads();
  if (threadIdx.x < 64) {
    int c = threadIdx.x;
    double S  = red[0][c] + red[1][c];
    double SS = red[0][64 + c] + red[1][64 + c];
    const double CNT = 16384.0;
    double m = S / CNT, var = SS / CNT - m * m;
    double rs = 1.0 / sqrt(var + 1e-5);
    double g = (double)bn_g[c];
    bn2s[c] = (float)(g * rs);
    bn2s[64 + c] = (float)((double)bn_be[c] - m * g * rs);
  }
}

// ---------------------------------------------------------------- cost_mod + q/k/v projections (fused)
__global__ __launch_bounds__(192) void qkv_cm(const float* __restrict__ cost,
    const float* __restrict__ pcT, const float* __restrict__ bn2s,
    const float* __restrict__ wq, const float* __restrict__ bq,
    const float* __restrict__ wk, const float* __restrict__ bk,
    const float* __restrict__ wv, const float* __restrict__ bv,
    float* __restrict__ qT, float* __restrict__ kT, float* __restrict__ vT) {
  int w = threadIdx.x / 64, lane = threadIdx.x & 63;
  const float* W  = (w == 0) ? wq : (w == 1) ? wk : wv;
  const float* Bb = (w == 0) ? bq : (w == 1) ? bk : bv;
  float* O        = (w == 0) ? qT : (w == 1) ? kT : vT;
  float wr[64];
  #pragma unroll
  for (int j = 0; j < 16; j++) {
    float4 a = *(const float4*)(W + (size_t)lane * 64 + 4 * j);
    wr[4*j] = a.x; wr[4*j+1] = a.y; wr[4*j+2] = a.z; wr[4*j+3] = a.w;
  }
  float bl = Bb[lane];
  __shared__ float cm[4][64];
  if (w == 0) {                        // stage cost_mod rows for 4 points
    float sc = bn2s[lane], sh = bn2s[64 + lane];
    #pragma unroll
    for (int pi = 0; pi < 4; ++pi) {
      size_t g = (size_t)blockIdx.x * 4 + pi;
      int b = (int)(g >> 13), n = (int)(g & (NPT - 1));
      float cv = cost[(size_t)b * NCH * NPT + (size_t)lane * NPT + n];
      float ca = fmaf(pcT[g * 64 + lane], sc, sh);
      ca = (ca >= 0.f) ? ca : 0.1f * ca;
      cm[pi][lane] = cv + ca;
    }
  }
  __syncthreads();
  #pragma unroll
  for (int pi = 0; pi < 4; ++pi) {
    size_t g = (size_t)blockIdx.x * 4 + pi;
    float acc = 0.f;
    #pragma unroll
    for (int j = 0; j < 16; j++) {
      float4 cv = *(const float4*)&cm[pi][4 * j];
      acc = fmaf(wr[4*j], cv.x, fmaf(wr[4*j+1], cv.y, fmaf(wr[4*j+2], cv.z, fmaf(wr[4*j+3], cv.w, acc))));
    }
    O[g * 64 + lane] = acc + bl;
  }
}

// ---------------------------------------------------------------- attention
__global__ __launch_bounds__(256) void attn_k(const float4* __restrict__ xyzw,
    const int* __restrict__ knn, const float* __restrict__ qT,
    const float* __restrict__ kT, const float* __restrict__ vT,
    const float* __restrict__ wpos, const float* __restrict__ bpos,
    float* __restrict__ out) {
  int w = threadIdx.x >> 6, lane = threadIdx.x & 63;
  size_t g = (size_t)blockIdx.x * 4 + w;
  int b = (int)(g >> 13), n = (int)(g & (NPT - 1));
  const float4* xb = xyzw + ((size_t)b << 13);
  float wp0 = wpos[3 * lane], wp1 = wpos[3 * lane + 1], wp2 = wpos[3 * lane + 2];
  float bp = bpos[lane];
  float4 pq = xb[n];
  float qd = qT[g * 64 + lane];
  const int* kn = knn + g * NKNN;
  float sc[16], vp[16];
  #pragma unroll
  for (int k = 0; k < 16; k++) {
    int nb = kn[k];
    float4 pcd = xb[nb];
    float ox = pcd.x - pq.x, oy = pcd.y - pq.y, oz = pcd.z - pq.z;
    float pos = fmaf(wp0, ox, fmaf(wp1, oy, wp2 * oz)) + bp;
    size_t nbi = (((size_t)b << 13) + nb) * 64 + lane;
    float kk = kT[nbi] + pos;
    float vv = vT[nbi] + pos;
    float p = qd * kk;
    #pragma unroll
    for (int off = 32; off; off >>= 1) p += __shfl_xor(p, off);
    sc[k] = p * 0.125f;
    vp[k] = vv;
  }
  float m = sc[0];
  #pragma unroll
  for (int k = 1; k < 16; k++) m = fmaxf(m, sc[k]);
  float sum = 0.f;
  #pragma unroll
  for (int k = 0; k < 16; k++) { sc[k] = __expf(sc[k] - m); sum += sc[k]; }
  float inv = 1.0f / sum;
  float od = 0.f;
  #pragma unroll
  for (int k = 0; k < 16; k++) od = fmaf(sc[k] * inv, vp[k], od);
  out[((size_t)b * 64 + lane) * NPT + n] = od;
}

// ---------------------------------------------------------------- launch
extern "C" void kernel_launch(void* const* d_in, const int* in_sizes, int n_in,
                              void* d_out, int out_size, void* d_ws, size_t ws_size,
                              hipStream_t stream) {
  (void)in_sizes; (void)n_in; (void)out_size; (void)ws_size;
  const float* xyz    = (const float*)d_in[0];
  const float* points = (const float*)d_in[1];
  const float* cost   = (const float*)d_in[2];
  const float* wn_w   = (const float*)d_in[3];
  const float* wn_b   = (const float*)d_in[4];
  const float* wn_g   = (const float*)d_in[5];
  const float* wn_be  = (const float*)d_in[6];
  const float* lin_w  = (const float*)d_in[7];
  const float* lin_b  = (const float*)d_in[8];
  const float* bn_g   = (const float*)d_in[9];
  const float* bn_be  = (const float*)d_in[10];
  const float* wq     = (const float*)d_in[11];
  const float* bq     = (const float*)d_in[12];
  const float* wk     = (const float*)d_in[13];
  const float* bk     = (const float*)d_in[14];
  const float* wv     = (const float*)d_in[15];
  const float* bv     = (const float*)d_in[16];
  const float* wpos   = (const float*)d_in[17];
  const float* bpos   = (const float*)d_in[18];
  float* out = (float*)d_out;
  char* ws = (char*)d_ws;

  int*    knn  = (int*)   (ws + OFF_KNN);
  float4* xyzw = (float4*)(ws + OFF_XYZW);
  double* bn1p = (double*)(ws + OFF_BN1P);
  float*  bn1s = (float*) (ws + OFF_BN1S);
  double* bn2p = (double*)(ws + OFF_BN2P);
  float*  bn2s = (float*) (ws + OFF_BN2S);
  float*  lwT  = (float*) (ws + OFF_LWT);
  float* diffT = (float*) (ws + OFF_DIFFT);
  float* pcT   = (float*) (ws + OFF_PCT);
  float* qT    = (float*) (ws + OFF_QT);
  float* kT    = (float*) (ws + OFF_KT);
  float* vT    = (float*) (ws + OFF_VT);

  prep       <<<dim3(328),     dim3(256),   0, stream>>>(xyz, cost, points, lin_w,
                                                         xyzw, diffT, lwT);
  knn_kernel <<<dim3(2048),    dim3(256),   0, stream>>>(xyzw, knn);
  bn1_partial<<<dim3(512),     dim3(256),   0, stream>>>(xyzw, knn, wn_w, wn_b, bn1p);
  bn1_final  <<<dim3(1),       dim3(256),   0, stream>>>(bn1p, wn_g, wn_be, bn1s);
  pointconv  <<<dim3(1024),    dim3(256),   0, stream>>>(xyzw, knn, diffT, lwT, lin_b,
                                                         bn1s, wn_w, wn_b, pcT);
  bn2_partial<<<dim3(64),      dim3(256),   0, stream>>>(pcT, bn2p);
  bn2_final  <<<dim3(1),       dim3(256),   0, stream>>>(bn2p, bn_g, bn_be, bn2s);
  qkv_cm     <<<dim3(4096),    dim3(192),   0, stream>>>(cost, pcT, bn2s, wq, bq, wk, bk,
                                                         wv, bv, qT, kT, vT);
  attn_k     <<<dim3(4096),    dim3(256),   0, stream>>>(xyzw, knn, qT, kT, vT, wpos, bpos, out);
}